// Round 9
// baseline (2670.213 us; speedup 1.0000x reference)
//
#include <hip/hip_runtime.h>
#include <math.h>

#define QLEN 512
#define NB   64
#define DD   128
#define HH   256
#define WOUT 64
#define PI_F 3.14159265358979323846f

__device__ __forceinline__ float sigmf(float x){ return 1.0f/(1.0f+expf(-x)); }
__device__ __forceinline__ float geluf(float x){ return 0.5f*x*(1.0f+erff(x*0.7071067811865476f)); }

// ---------------------------------------------------------------------------
// Fused weight-prep (1 launch). tconv: (O,I,K) -> (K,I,O). pack_quads:
// (R,C) -> float4[j4*R + r]. fp32 MANDATORY everywhere — fp32 reordering
// alone gives absmax 0.06-0.125 vs threshold 0.35 (the pipeline amplifies
// mid-network noise ~1e6x); bf16 anywhere upstream decorrelates (round 2).
__device__ __forceinline__ void tconv_elem(const float* __restrict__ in,
                                           float* __restrict__ out,
                                           int idx, int O, int I, int K) {
    int o = idx % O; int rest = idx / O; int i = rest % I; int k = rest / I;
    out[idx] = in[(o*I + i)*K + k];
}
__device__ __forceinline__ void pq_elem(const float* __restrict__ in,
                                        float4* __restrict__ out,
                                        int idx, int R, int C) {
    int r = idx % R, j4 = idx / R;
    const float* p = in + (size_t)r*C + 4*j4;
    float4 v; v.x = p[0]; v.y = p[1]; v.z = p[2]; v.w = p[3];
    out[idx] = v;
}
__global__ __launch_bounds__(256) void prep_k(
    const float* __restrict__ inp_w, const float* __restrict__ b0c1w,
    const float* __restrict__ b0c2w, const float* __restrict__ b1c1w,
    const float* __restrict__ b1c2w, const float* __restrict__ gainw,
    const float* __restrict__ riw,  const float* __restrict__ wih,
    const float* __restrict__ whh,
    float* __restrict__ Wt_inp,  float* __restrict__ Wt_b0c1,
    float* __restrict__ Wt_b0c2, float* __restrict__ Wt_b1c1,
    float* __restrict__ Wt_b1c2, float* __restrict__ Wt_gain,
    float4* __restrict__ Wri4, float4* __restrict__ Wih4, float4* __restrict__ Whh4)
{
    int idx = blockIdx.x*256 + threadIdx.x;
    if      (idx <   98304) tconv_elem(inp_w, Wt_inp,  idx,          256, 384, 1);
    else if (idx <  294912) tconv_elem(b0c1w, Wt_b0c1, idx -  98304, 256, 256, 3);
    else if (idx <  491520) tconv_elem(b0c2w, Wt_b0c2, idx - 294912, 256, 256, 3);
    else if (idx <  688128) tconv_elem(b1c1w, Wt_b1c1, idx - 491520, 256, 256, 3);
    else if (idx <  884736) tconv_elem(b1c2w, Wt_b1c2, idx - 688128, 256, 256, 3);
    else if (idx <  917504) tconv_elem(gainw, Wt_gain, idx - 884736, 128, 256, 1);
    else if (idx <  942080) pq_elem(riw, Wri4, idx - 917504, 256, 384);
    else if (idx <  991232) pq_elem(wih, Wih4, idx - 942080, 768, 256);
    else if (idx < 1040384) pq_elem(whh, Whh4, idx - 991232, 768, 256);
}

// ---------------------------------------------------------------------------
// Conv-as-GEMM, TM=32, 256 threads, 8 rows/wave (round-6 proven shape) +
// round-9 SOFTWARE-PIPELINED weight loads: the (k,ci) loop is flattened and
// the 4 weight float4s double-buffered in registers, so the next step's L2
// loads (~200+ cyc) issue before the current step's 128 FMAs (~256 cyc
// cover). Evidence: round-6 VALUBusy 22%, VGPR=52 (no compiler prefetch) —
// latency-bound, NOT L2-BW-bound (rounds 7/8 falsified that: +waves and
// +LDS-staging both regressed). FMA order per output unchanged -> bitwise-
// identical results. VGPR ~85 < 128 keeps 4 waves/SIMD.
template<int CIN, int COUT, int KS, int DIL, int ACT, int FEATS>
__global__ __launch_bounds__(256) void conv_pipe_k(
    const float* __restrict__ X, const float* __restrict__ Wt,
    const float* __restrict__ bias, float* __restrict__ Y)
{
    constexpr int TM   = 32;
    constexpr int HALO = (KS == 3) ? DIL : 0;
    constexpr int ROWS = TM + 2*HALO;
    constexpr int CPT  = COUT/64;
    constexpr int CIN4 = CIN/4;
    constexpr int M    = KS*CIN4;
    __shared__ __align__(16) float As[ROWS*CIN];

    const int b  = blockIdx.y;
    const int t0 = blockIdx.x * TM;
    const int tid = threadIdx.x;

    if constexpr (FEATS) {
        for (int idx = tid; idx < TM*DD; idx += 256) {
            int r = idx >> 7, d = idx & (DD-1);
            int t = t0 + r;
            const float* xr = X + ((size_t)b*QLEN + t)*DD + d;
            float x    = xr[0];
            float xm1  = (t >= 1) ? xr[-DD]   : 0.f;
            float xm2  = (t >= 2) ? xr[-2*DD] : 0.f;
            float dy   = (t >= 1) ? (x - xm1)   : 0.f;
            float dym1 = (t >= 2) ? (xm1 - xm2) : 0.f;
            float ddy  = (t >= 1) ? (dy - dym1) : 0.f;
            As[r*CIN + d]        = x;
            As[r*CIN + DD + d]   = dy;
            As[r*CIN + 2*DD + d] = ddy;
        }
    } else {
        for (int idx = tid; idx < ROWS*(CIN/4); idx += 256) {
            int r = idx / (CIN/4), c4 = idx % (CIN/4);
            int gr = t0 + r - HALO;
            gr = gr < 0 ? 0 : (gr > QLEN-1 ? QLEN-1 : gr);   // edge padding
            float4 v = reinterpret_cast<const float4*>(X + ((size_t)b*QLEN + gr)*CIN)[c4];
            reinterpret_cast<float4*>(As)[r*(CIN/4) + c4] = v;
        }
    }
    __syncthreads();

    const int lane = tid & 63, rg = tid >> 6;
    const int c0 = lane * CPT;
    const int r0 = rg * 8;

    float acc[8][CPT];
    #pragma unroll
    for (int j = 0; j < 8; ++j)
        #pragma unroll
        for (int p = 0; p < CPT; ++p) acc[j][p] = 0.f;

    float w[2][4][CPT];
    // prologue: load m=0 (k=0, ci=0)
    {
        const float* W0 = Wt + c0;
        #pragma unroll
        for (int q = 0; q < 4; ++q) {
            if constexpr (CPT == 4) {
                float4 wv = *reinterpret_cast<const float4*>(W0 + (size_t)q*COUT);
                w[0][q][0]=wv.x; w[0][q][1]=wv.y; w[0][q][2]=wv.z; w[0][q][3]=wv.w;
            } else {
                float2 wv = *reinterpret_cast<const float2*>(W0 + (size_t)q*COUT);
                w[0][q][0]=wv.x; w[0][q][1]=wv.y;
            }
        }
    }

    for (int m = 0; m < M; ++m) {
        const int cur = m & 1, nxt = cur ^ 1;
        // prefetch next step's weights while current FMAs run
        if (m + 1 < M) {
            const int m1  = m + 1;
            const int k1  = m1 / CIN4, ci1 = (m1 % CIN4) * 4;
            const float* Wn = Wt + ((size_t)k1*CIN + ci1)*COUT + c0;
            #pragma unroll
            for (int q = 0; q < 4; ++q) {
                if constexpr (CPT == 4) {
                    float4 wv = *reinterpret_cast<const float4*>(Wn + (size_t)q*COUT);
                    w[nxt][q][0]=wv.x; w[nxt][q][1]=wv.y; w[nxt][q][2]=wv.z; w[nxt][q][3]=wv.w;
                } else {
                    float2 wv = *reinterpret_cast<const float2*>(Wn + (size_t)q*COUT);
                    w[nxt][q][0]=wv.x; w[nxt][q][1]=wv.y;
                }
            }
        }
        const int k  = m / CIN4, ci = (m % CIN4) * 4;
        #pragma unroll
        for (int j = 0; j < 8; ++j) {
            const float4 a = *reinterpret_cast<const float4*>(&As[(r0 + j + k*DIL)*CIN + ci]);
            #pragma unroll
            for (int p = 0; p < CPT; ++p) {
                acc[j][p] = fmaf(a.x, w[cur][0][p], acc[j][p]);
                acc[j][p] = fmaf(a.y, w[cur][1][p], acc[j][p]);
                acc[j][p] = fmaf(a.z, w[cur][2][p], acc[j][p]);
                acc[j][p] = fmaf(a.w, w[cur][3][p], acc[j][p]);
            }
        }
    }

    float bv[CPT];
    #pragma unroll
    for (int p = 0; p < CPT; ++p) bv[p] = bias[c0 + p];

    #pragma unroll
    for (int j = 0; j < 8; ++j) {
        float o[CPT];
        #pragma unroll
        for (int p = 0; p < CPT; ++p) {
            float v = acc[j][p] + bv[p];
            if constexpr (ACT == 1) v = geluf(v);
            if constexpr (ACT == 2) v = sigmf(v);
            o[p] = v;
        }
        float* yr = Y + ((size_t)b*QLEN + t0 + r0 + j)*COUT + c0;
        if constexpr (CPT == 4) {
            float4 ov; ov.x=o[0]; ov.y=o[1]; ov.z=o[2]; ov.w=o[3];
            *reinterpret_cast<float4*>(yr) = ov;
        } else {
            float2 ov; ov.x=o[0]; ov.y=o[1];
            *reinterpret_cast<float2*>(yr) = ov;
        }
    }
}

// ---------------------------------------------------------------------------
// LayerNorm over H=256 per (b,t) row with residual add.
__global__ __launch_bounds__(256) void ln_k(
    const float* __restrict__ X, const float* __restrict__ R,
    const float* __restrict__ w, const float* __restrict__ b,
    float* __restrict__ Y)
{
    int row  = blockIdx.x*4 + (threadIdx.x >> 6);
    int lane = threadIdx.x & 63;
    float4 v = reinterpret_cast<const float4*>(X + (size_t)row*HH)[lane];
    float4 rv = reinterpret_cast<const float4*>(R + (size_t)row*HH)[lane];
    v.x += rv.x; v.y += rv.y; v.z += rv.z; v.w += rv.w;
    float s = v.x + v.y + v.z + v.w;
    #pragma unroll
    for (int off = 32; off > 0; off >>= 1) s += __shfl_xor(s, off);
    float m = s * (1.0f/HH);
    float dx=v.x-m, dy=v.y-m, dz=v.z-m, dw=v.w-m;
    float q = dx*dx + dy*dy + dz*dz + dw*dw;
    #pragma unroll
    for (int off = 32; off > 0; off >>= 1) q += __shfl_xor(q, off);
    float inv = rsqrtf(q*(1.0f/HH) + 1e-5f);
    float4 wv = reinterpret_cast<const float4*>(w)[lane];
    float4 bv = reinterpret_cast<const float4*>(b)[lane];
    float4 o;
    o.x = dx*inv*wv.x + bv.x;
    o.y = dy*inv*wv.y + bv.y;
    o.z = dz*inv*wv.z + bv.z;
    o.w = dw*inv*wv.w + bv.w;
    reinterpret_cast<float4*>(Y + (size_t)row*HH)[lane] = o;
}

// ---------------------------------------------------------------------------
// Fused output-LN + rho/phi.
__global__ __launch_bounds__(256) void ln_rp_k(
    const float* __restrict__ X, const float* __restrict__ w, const float* __restrict__ b,
    const float* __restrict__ rpw, const float* __restrict__ rpb,
    float* __restrict__ Y, float* __restrict__ rho, float* __restrict__ phi)
{
    int row  = blockIdx.x*4 + (threadIdx.x >> 6);
    int lane = threadIdx.x & 63;
    float4 v = reinterpret_cast<const float4*>(X + (size_t)row*HH)[lane];
    float s = v.x + v.y + v.z + v.w;
    #pragma unroll
    for (int off = 32; off > 0; off >>= 1) s += __shfl_xor(s, off);
    float m = s * (1.0f/HH);
    float dx=v.x-m, dy=v.y-m, dz=v.z-m, dw=v.w-m;
    float q = dx*dx + dy*dy + dz*dz + dw*dw;
    #pragma unroll
    for (int off = 32; off > 0; off >>= 1) q += __shfl_xor(q, off);
    float inv = rsqrtf(q*(1.0f/HH) + 1e-5f);
    float4 wv = reinterpret_cast<const float4*>(w)[lane];
    float4 bv = reinterpret_cast<const float4*>(b)[lane];
    float4 o;
    o.x = dx*inv*wv.x + bv.x;
    o.y = dy*inv*wv.y + bv.y;
    o.z = dz*inv*wv.z + bv.z;
    o.w = dw*inv*wv.w + bv.w;
    reinterpret_cast<float4*>(Y + (size_t)row*HH)[lane] = o;

    float4 w0 = reinterpret_cast<const float4*>(rpw)[lane];
    float4 w1 = reinterpret_cast<const float4*>(rpw + HH)[lane];
    float d0 = o.x*w0.x + o.y*w0.y + o.z*w0.z + o.w*w0.w;
    float d1 = o.x*w1.x + o.y*w1.y + o.z*w1.z + o.w*w1.w;
    #pragma unroll
    for (int off = 32; off > 0; off >>= 1) { d0 += __shfl_xor(d0, off); d1 += __shfl_xor(d1, off); }
    if (lane == 0) {
        rho[row] = 1.25f * sigmf(d0 + rpb[0]);
        phi[row] = PI_F * tanhf(d1 + rpb[1]);
    }
}

// ---------------------------------------------------------------------------
// Small GEMM (Kg, COUT=128) — round-6 proven 256-thread version.
template<int CIN, int COUT, int KS, int DIL, int ACT, int FEATS>
__global__ __launch_bounds__(256) void conv_gemm_k(
    const float* __restrict__ X, const float* __restrict__ Wt,
    const float* __restrict__ bias, float* __restrict__ Y)
{
    constexpr int TM   = 32;
    constexpr int HALO = (KS == 3) ? DIL : 0;
    constexpr int ROWS = TM + 2*HALO;
    constexpr int CPT  = COUT/64;
    __shared__ __align__(16) float As[ROWS*CIN];

    const int b  = blockIdx.y;
    const int t0 = blockIdx.x * TM;
    const int tid = threadIdx.x;

    for (int idx = tid; idx < ROWS*(CIN/4); idx += 256) {
        int r = idx / (CIN/4), c4 = idx % (CIN/4);
        int gr = t0 + r - HALO;
        gr = gr < 0 ? 0 : (gr > QLEN-1 ? QLEN-1 : gr);
        float4 v = reinterpret_cast<const float4*>(X + ((size_t)b*QLEN + gr)*CIN)[c4];
        reinterpret_cast<float4*>(As)[r*(CIN/4) + c4] = v;
    }
    __syncthreads();

    const int lane = tid & 63, rg = tid >> 6;
    const int c0 = lane * CPT;
    const int r0 = rg * 8;

    float acc[8][CPT];
    #pragma unroll
    for (int j = 0; j < 8; ++j)
        #pragma unroll
        for (int p = 0; p < CPT; ++p) acc[j][p] = 0.f;

    for (int k = 0; k < KS; ++k) {
        const float* Wk = Wt + (size_t)k*CIN*COUT + c0;
        for (int ci = 0; ci < CIN; ci += 4) {
            float w[4][CPT];
            #pragma unroll
            for (int q = 0; q < 4; ++q) {
                if constexpr (CPT == 4) {
                    float4 wv = *reinterpret_cast<const float4*>(Wk + (size_t)(ci+q)*COUT);
                    w[q][0]=wv.x; w[q][1]=wv.y; w[q][2]=wv.z; w[q][3]=wv.w;
                } else {
                    float2 wv = *reinterpret_cast<const float2*>(Wk + (size_t)(ci+q)*COUT);
                    w[q][0]=wv.x; w[q][1]=wv.y;
                }
            }
            #pragma unroll
            for (int j = 0; j < 8; ++j) {
                const float4 a = *reinterpret_cast<const float4*>(&As[(r0 + j + k*DIL)*CIN + ci]);
                #pragma unroll
                for (int p = 0; p < CPT; ++p) {
                    acc[j][p] = fmaf(a.x, w[0][p], acc[j][p]);
                    acc[j][p] = fmaf(a.y, w[1][p], acc[j][p]);
                    acc[j][p] = fmaf(a.z, w[2][p], acc[j][p]);
                    acc[j][p] = fmaf(a.w, w[3][p], acc[j][p]);
                }
            }
        }
    }

    float bv[CPT];
    #pragma unroll
    for (int p = 0; p < CPT; ++p) bv[p] = bias[c0 + p];

    #pragma unroll
    for (int j = 0; j < 8; ++j) {
        float o[CPT];
        #pragma unroll
        for (int p = 0; p < CPT; ++p) {
            float v = acc[j][p] + bv[p];
            if constexpr (ACT == 1) v = geluf(v);
            if constexpr (ACT == 2) v = sigmf(v);
            o[p] = v;
        }
        float* yr = Y + ((size_t)b*QLEN + t0 + r0 + j)*COUT + c0;
        if constexpr (CPT == 4) {
            float4 ov; ov.x=o[0]; ov.y=o[1]; ov.z=o[2]; ov.w=o[3];
            *reinterpret_cast<float4*>(yr) = ov;
        } else {
            float2 ov; ov.x=o[0]; ov.y=o[1];
            *reinterpret_cast<float2*>(yr) = ov;
        }
    }
}

// ---------------------------------------------------------------------------
// Kalman scan with next-step prefetch.
__global__ __launch_bounds__(64) void kalman_k(
    const float* __restrict__ Xin, const float* __restrict__ Kg,
    const float* __restrict__ rho_a, const float* __restrict__ phi_a,
    float* __restrict__ xpost)
{
    int b = blockIdx.x, l = threadIdx.x;
    const float* xb = Xin + (size_t)b*QLEN*DD;
    float re = xb[l], im = xb[64 + l];

    float rho_c = rho_a[b*QLEN], phi_c = phi_a[b*QLEN];
    const float* kg0 = Kg + (size_t)b*QLEN*DD;
    float kr_c = kg0[l], ki_c = kg0[64 + l];
    float y0_c = xb[l],  y1_c = xb[64 + l];

    for (int t = 0; t < QLEN; ++t) {
        float rho_n = 0.f, phi_n = 0.f, kr_n = 0.f, ki_n = 0.f, y0_n = 0.f, y1_n = 0.f;
        if (t + 1 < QLEN) {
            rho_n = rho_a[b*QLEN + t + 1];
            phi_n = phi_a[b*QLEN + t + 1];
            const float* kg = Kg + ((size_t)b*QLEN + t + 1)*DD;
            const float* yr = xb + (size_t)(t + 1)*DD;
            kr_n = kg[l]; ki_n = kg[64 + l];
            y0_n = yr[l]; y1_n = yr[64 + l];
        }
        float sn, cs; sincosf(phi_c, &sn, &cs);
        float pr = rho_c*(cs*re - sn*im);
        float pi = rho_c*(sn*re + cs*im);
        re = pr + kr_c*(y0_c - pr);
        im = pi + ki_c*(y1_c - pi);
        rho_c = rho_n; phi_c = phi_n; kr_c = kr_n; ki_c = ki_n; y0_c = y0_n; y1_c = y1_n;
    }
    xpost[b*DD + l]      = re;
    xpost[b*DD + 64 + l] = im;
}

// ---------------------------------------------------------------------------
// Rollout v5 (round-6 proven): one block/batch, 1024 threads, fp32 weights
// (precision-mandatory). ~119 GB/s/CU weight ingest = 83% of per-CU L2 port,
// near the 1-block/batch structural floor (876 us). Multi-block needs agent
// fences that invalidate L2 (round 4: FETCH 7.8MB -> 2.75GB, 2.4x slower).
__device__ __forceinline__ float bsum16(float v, float* red) {
    #pragma unroll
    for (int off = 32; off > 0; off >>= 1) v += __shfl_xor(v, off);
    __syncthreads();
    if ((threadIdx.x & 63) == 0) red[threadIdx.x >> 6] = v;
    __syncthreads();
    float s = 0.f;
    #pragma unroll
    for (int i = 0; i < 16; ++i) s += red[i];
    return s;
}
__device__ __forceinline__ float2 bsum16_2(float a, float b, float* red) {
    #pragma unroll
    for (int off = 32; off > 0; off >>= 1) { a += __shfl_xor(a, off); b += __shfl_xor(b, off); }
    __syncthreads();
    if ((threadIdx.x & 63) == 0) { red[threadIdx.x >> 6] = a; red[16 + (threadIdx.x >> 6)] = b; }
    __syncthreads();
    float sa = 0.f, sb = 0.f;
    #pragma unroll
    for (int i = 0; i < 16; ++i) { sa += red[i]; sb += red[16 + i]; }
    float2 r; r.x = sa; r.y = sb; return r;
}

__global__ __launch_bounds__(1024) void rollout_k5(
    const float* __restrict__ Hs, const float* __restrict__ xpost,
    const float4* __restrict__ Wri4,          // [96*256]  (j4, o)
    const float* __restrict__ rib,
    const float4* __restrict__ Wih4,          // [64*768]  (j4, gate_o)
    const float4* __restrict__ Whh4,          // [64*768]
    const float* __restrict__ bih, const float* __restrict__ bhh,
    const float* __restrict__ lnw, const float* __restrict__ lnb,
    const float* __restrict__ rpw, const float* __restrict__ rpb,
    float* __restrict__ out)
{
    __shared__ __align__(16) float hc[384];    // h_r[0:256] ++ curr[256:384]
    __shared__ __align__(16) float zsh[256];
    __shared__ float zpart[4][256];
    __shared__ float gpart[6][4][256];
    __shared__ float red[32];

    const int tid = threadIdx.x;
    const int o = tid & 255, p = tid >> 8;
    const int b = blockIdx.x;

    if (p == 0) hc[o] = Hs[((size_t)b*QLEN + QLEN-1)*HH + o];
    if (p == 1 && o < DD) hc[HH + o] = xpost[b*DD + o];

    const float bi0 = bih[o],    bi1 = bih[HH+o], bi2 = bih[2*HH+o];
    const float bh0 = bhh[o],    bh1 = bhh[HH+o], bh2 = bhh[2*HH+o];
    const float rb  = rib[o];
    const float lw  = lnw[o],    lb  = lnb[o];
    const float rw0 = rpw[o],    rw1 = rpw[HH+o];
    const float rpb0 = rpb[0],   rpb1 = rpb[1];
    const float4* hc4 = reinterpret_cast<const float4*>(hc);
    const float4* zf4 = reinterpret_cast<const float4*>(zsh);
    __syncthreads();

    for (int s = 0; s < WOUT; ++s) {
        // ---- Phase A: z-partials (Wri) + e-partials (Whh) — both need only h
        float az = 0.f;
        {
            const float4* wp = Wri4 + (size_t)(p*24)*256 + o;
            #pragma unroll 8
            for (int j4 = 0; j4 < 24; ++j4) {
                float4 w = wp[(size_t)j4*256];
                float4 h = hc4[p*24 + j4];
                az = fmaf(w.x, h.x, az); az = fmaf(w.y, h.y, az);
                az = fmaf(w.z, h.z, az); az = fmaf(w.w, h.w, az);
            }
        }
        float e0=0.f, e1=0.f, e2=0.f;
        {
            const float4* whp = Whh4 + (size_t)(p*16)*768 + o;
            #pragma unroll 4
            for (int j4 = 0; j4 < 16; ++j4) {
                float4 h = hc4[p*16 + j4];
                float4 wd = whp[(size_t)j4*768];
                float4 we = whp[(size_t)j4*768 + 256];
                float4 wf = whp[(size_t)j4*768 + 512];
                e0 = fmaf(wd.x,h.x,e0); e0 = fmaf(wd.y,h.y,e0); e0 = fmaf(wd.z,h.z,e0); e0 = fmaf(wd.w,h.w,e0);
                e1 = fmaf(we.x,h.x,e1); e1 = fmaf(we.y,h.y,e1); e1 = fmaf(we.z,h.z,e1); e1 = fmaf(we.w,h.w,e1);
                e2 = fmaf(wf.x,h.x,e2); e2 = fmaf(wf.y,h.y,e2); e2 = fmaf(wf.z,h.z,e2); e2 = fmaf(wf.w,h.w,e2);
            }
        }
        zpart[p][o] = az;
        gpart[3][p][o]=e0; gpart[4][p][o]=e1; gpart[5][p][o]=e2;
        __syncthreads();
        if (p == 0)
            zsh[o] = tanhf(zpart[0][o]+zpart[1][o]+zpart[2][o]+zpart[3][o] + rb);
        __syncthreads();

        // ---- Phase B: g-partials (Wih)
        float g0=0.f, g1=0.f, g2=0.f;
        {
            const float4* wip = Wih4 + (size_t)(p*16)*768 + o;
            #pragma unroll 4
            for (int j4 = 0; j4 < 16; ++j4) {
                float4 z = zf4[p*16 + j4];
                float4 wa = wip[(size_t)j4*768];
                float4 wb = wip[(size_t)j4*768 + 256];
                float4 wc = wip[(size_t)j4*768 + 512];
                g0 = fmaf(wa.x,z.x,g0); g0 = fmaf(wa.y,z.y,g0); g0 = fmaf(wa.z,z.z,g0); g0 = fmaf(wa.w,z.w,g0);
                g1 = fmaf(wb.x,z.x,g1); g1 = fmaf(wb.y,z.y,g1); g1 = fmaf(wb.z,z.z,g1); g1 = fmaf(wb.w,z.w,g1);
                g2 = fmaf(wc.x,z.x,g2); g2 = fmaf(wc.y,z.y,g2); g2 = fmaf(wc.z,z.z,g2); g2 = fmaf(wc.w,z.w,g2);
            }
        }
        gpart[0][p][o]=g0; gpart[1][p][o]=g1; gpart[2][p][o]=g2;
        __syncthreads();

        float go = 0.f;
        if (p == 0) {
            float G0 = gpart[0][0][o]+gpart[0][1][o]+gpart[0][2][o]+gpart[0][3][o] + bi0;
            float G1 = gpart[1][0][o]+gpart[1][1][o]+gpart[1][2][o]+gpart[1][3][o] + bi1;
            float G2 = gpart[2][0][o]+gpart[2][1][o]+gpart[2][2][o]+gpart[2][3][o] + bi2;
            float E0 = gpart[3][0][o]+gpart[3][1][o]+gpart[3][2][o]+gpart[3][3][o] + bh0;
            float E1 = gpart[4][0][o]+gpart[4][1][o]+gpart[4][2][o]+gpart[4][3][o] + bh1;
            float E2 = gpart[5][0][o]+gpart[5][1][o]+gpart[5][2][o]+gpart[5][3][o] + bh2;
            float r  = sigmf(G0 + E0);
            float zg = sigmf(G1 + E1);
            float n  = tanhf(G2 + r*E2);
            go = (1.0f - zg)*n + zg*hc[o];
        }

        // ---- LN over 256 (two-pass, matches reference order)
        float m   = bsum16(go, red) * (1.0f/HH);
        float d   = (p == 0) ? (go - m) : 0.f;
        float var = bsum16(d*d, red) * (1.0f/HH);
        float hn  = (p == 0) ? (d * rsqrtf(var + 1e-5f) * lw + lb) : 0.f;

        // ---- rho/phi: fused dual reduction
        float2 ps = bsum16_2((p == 0) ? hn*rw0 : 0.f, (p == 0) ? hn*rw1 : 0.f, red);
        float rho = 1.25f * sigmf(ps.x + rpb0);
        float phi = PI_F * tanhf(ps.y + rpb1);
        float sn, cs; sincosf(phi, &sn, &cs);

        if (p == 0) hc[o] = hn;
        if (tid < 64) {
            float cre = hc[HH + tid], cim = hc[HH + 64 + tid];
            float nr = rho*(cs*cre - sn*cim);
            float ni = rho*(sn*cre + cs*cim);
            hc[HH + tid] = nr; hc[HH + 64 + tid] = ni;
            float* ob = out + ((size_t)b*WOUT + s)*DD;
            ob[tid] = nr; ob[64 + tid] = ni;
        }
        __syncthreads();
    }
}

// ---------------------------------------------------------------------------
extern "C" void kernel_launch(void* const* d_in, const int* in_sizes, int n_in,
                              void* d_out, int out_size, void* d_ws, size_t ws_size,
                              hipStream_t stream)
{
    const float* x_in   = (const float*)d_in[0];
    const float* inp_w  = (const float*)d_in[2];
    const float* inp_b  = (const float*)d_in[3];
    const float* b0c1w  = (const float*)d_in[4];
    const float* b0c1b  = (const float*)d_in[5];
    const float* b0c2w  = (const float*)d_in[6];
    const float* b0c2b  = (const float*)d_in[7];
    const float* b0lnw  = (const float*)d_in[8];
    const float* b0lnb  = (const float*)d_in[9];
    const float* b1c1w  = (const float*)d_in[10];
    const float* b1c1b  = (const float*)d_in[11];
    const float* b1c2w  = (const float*)d_in[12];
    const float* b1c2b  = (const float*)d_in[13];
    const float* b1lnw  = (const float*)d_in[14];
    const float* b1lnb  = (const float*)d_in[15];
    const float* olnw   = (const float*)d_in[16];
    const float* olnb   = (const float*)d_in[17];
    const float* gainw  = (const float*)d_in[18];
    const float* gainb  = (const float*)d_in[19];
    const float* rpw    = (const float*)d_in[20];
    const float* rpb    = (const float*)d_in[21];
    const float* riw    = (const float*)d_in[22];
    const float* rib    = (const float*)d_in[23];
    const float* wih    = (const float*)d_in[24];
    const float* whh    = (const float*)d_in[25];
    const float* bih    = (const float*)d_in[26];
    const float* bhh    = (const float*)d_in[27];
    const float* rlnw   = (const float*)d_in[28];
    const float* rlnb   = (const float*)d_in[29];
    const float* rprw   = (const float*)d_in[30];
    const float* rprb   = (const float*)d_in[31];
    float* out = (float*)d_out;

    // workspace layout (floats)
    float* ws   = (float*)d_ws;
    float* buf0 = ws;                    // 8388608
    float* buf1 = ws +  8388608;         // 8388608
    float* buf2 = ws + 16777216;         // 8388608
    float* Kg    = buf2;                 // 4194304 (buf2 dead by then)
    float* rhoA  = buf2 + 4194304;       // 32768
    float* phiA  = rhoA + 32768;         // 32768
    float* xpost = phiA + 32768;         // 8192
    float* wts   = ws + 25165824;
    float* Wt_inp  = wts;                //  98304
    float* Wt_b0c1 = wts +   98304;      // 196608
    float* Wt_b0c2 = wts +  294912;      // 196608
    float* Wt_b1c1 = wts +  491520;      // 196608
    float* Wt_b1c2 = wts +  688128;      // 196608
    float* Wt_gain = wts +  884736;      //  32768
    float4* Wri4   = (float4*)(wts +  917504);   // 24576 float4
    float4* Wih4   = (float4*)(wts + 1015808);   // 49152 float4
    float4* Whh4   = (float4*)(wts + 1212416);   // 49152 float4
    // total ws use: 26574848 floats ~= 101.4 MB

    // ---- fused weight prep
    prep_k<<<4064, 256, 0, stream>>>(inp_w, b0c1w, b0c2w, b1c1w, b1c2w, gainw,
                                     riw, wih, whh,
                                     Wt_inp, Wt_b0c1, Wt_b0c2, Wt_b1c1, Wt_b1c2,
                                     Wt_gain, Wri4, Wih4, Whh4);

    dim3 cg32(QLEN/32, NB);

    // ---- input projection (feats built on the fly), pipelined
    conv_pipe_k<384,256,1,1,0,1><<<cg32, 256, 0, stream>>>(x_in, Wt_inp, inp_b, buf0);

    // ---- block 0 (dil=1), pipelined
    conv_pipe_k<256,256,3,1,1,0><<<cg32, 256, 0, stream>>>(buf0, Wt_b0c1, b0c1b, buf1);
    conv_pipe_k<256,256,3,1,1,0><<<cg32, 256, 0, stream>>>(buf1, Wt_b0c2, b0c2b, buf2);
    ln_k<<<NB*QLEN/4, 256, 0, stream>>>(buf0, buf2, b0lnw, b0lnb, buf1);

    // ---- block 1 (dil=2), pipelined
    conv_pipe_k<256,256,3,2,1,0><<<cg32, 256, 0, stream>>>(buf1, Wt_b1c1, b1c1b, buf0);
    conv_pipe_k<256,256,3,2,1,0><<<cg32, 256, 0, stream>>>(buf0, Wt_b1c2, b1c2b, buf2);
    ln_k<<<NB*QLEN/4, 256, 0, stream>>>(buf1, buf2, b1lnw, b1lnb, buf0);

    // ---- fused output LN + rho/phi: buf0 -> buf1, rhoA, phiA
    ln_rp_k<<<NB*QLEN/4, 256, 0, stream>>>(buf0, olnw, olnb, rpw, rpb,
                                           buf1, rhoA, phiA);

    // ---- Kg (sigmoid GEMM, small)
    conv_gemm_k<256,128,1,1,2,0><<<cg32, 256, 0, stream>>>(buf1, Wt_gain, gainb, Kg);

    // ---- Kalman scan (prefetch-pipelined)
    kalman_k<<<NB, 64, 0, stream>>>(x_in, Kg, rhoA, phiA, xpost);

    // ---- rollout v5 (fp32 precision-mandatory)
    rollout_k5<<<NB, 1024, 0, stream>>>(buf1, xpost, Wri4, rib, Wih4, Whh4,
                                        bih, bhh, rlnw, rlnb, rprw, rprb, out);
}

// Round 10
// 2180.618 us; speedup vs baseline: 1.2245x; 1.2245x over previous
//
#include <hip/hip_runtime.h>
#include <math.h>

#define QLEN 512
#define NB   64
#define DD   128
#define HH   256
#define WOUT 64
#define PI_F 3.14159265358979323846f

__device__ __forceinline__ float sigmf(float x){ return 1.0f/(1.0f+expf(-x)); }
__device__ __forceinline__ float geluf(float x){ return 0.5f*x*(1.0f+erff(x*0.7071067811865476f)); }

// ---------------------------------------------------------------------------
// Fused weight-prep (1 launch). tconv: (O,I,K) -> (K,I,O). pack_quads:
// (R,C) -> float4[j4*R + r]. fp32 MANDATORY everywhere — fp32 reordering
// alone gives absmax 0.06-0.125 vs threshold 0.35 (the pipeline amplifies
// mid-network noise ~1e6x); bf16 anywhere upstream decorrelates (round 2).
__device__ __forceinline__ void tconv_elem(const float* __restrict__ in,
                                           float* __restrict__ out,
                                           int idx, int O, int I, int K) {
    int o = idx % O; int rest = idx / O; int i = rest % I; int k = rest / I;
    out[idx] = in[(o*I + i)*K + k];
}
__device__ __forceinline__ void pq_elem(const float* __restrict__ in,
                                        float4* __restrict__ out,
                                        int idx, int R, int C) {
    int r = idx % R, j4 = idx / R;
    const float* p = in + (size_t)r*C + 4*j4;
    float4 v; v.x = p[0]; v.y = p[1]; v.z = p[2]; v.w = p[3];
    out[idx] = v;
}
__global__ __launch_bounds__(256) void prep_k(
    const float* __restrict__ inp_w, const float* __restrict__ b0c1w,
    const float* __restrict__ b0c2w, const float* __restrict__ b1c1w,
    const float* __restrict__ b1c2w, const float* __restrict__ gainw,
    const float* __restrict__ riw,  const float* __restrict__ wih,
    const float* __restrict__ whh,
    float* __restrict__ Wt_inp,  float* __restrict__ Wt_b0c1,
    float* __restrict__ Wt_b0c2, float* __restrict__ Wt_b1c1,
    float* __restrict__ Wt_b1c2, float* __restrict__ Wt_gain,
    float4* __restrict__ Wri4, float4* __restrict__ Wih4, float4* __restrict__ Whh4)
{
    int idx = blockIdx.x*256 + threadIdx.x;
    if      (idx <   98304) tconv_elem(inp_w, Wt_inp,  idx,          256, 384, 1);
    else if (idx <  294912) tconv_elem(b0c1w, Wt_b0c1, idx -  98304, 256, 256, 3);
    else if (idx <  491520) tconv_elem(b0c2w, Wt_b0c2, idx - 294912, 256, 256, 3);
    else if (idx <  688128) tconv_elem(b1c1w, Wt_b1c1, idx - 491520, 256, 256, 3);
    else if (idx <  884736) tconv_elem(b1c2w, Wt_b1c2, idx - 688128, 256, 256, 3);
    else if (idx <  917504) tconv_elem(gainw, Wt_gain, idx - 884736, 128, 256, 1);
    else if (idx <  942080) pq_elem(riw, Wri4, idx - 917504, 256, 384);
    else if (idx <  991232) pq_elem(wih, Wih4, idx - 942080, 768, 256);
    else if (idx < 1040384) pq_elem(whh, Whh4, idx - 991232, 768, 256);
}

// ---------------------------------------------------------------------------
// Conv-as-GEMM, TM=32, 256 threads, 8 rows/wave — the ROUND-6 PROVEN shape
// (2153 us total). Conv experiment ledger: TM=64 (-180us, LDS/occupancy),
// 512-thread (-340us, per-wave weight restream doubles), LDS-staged W
// (-250us, barrier+LDS pressure), manual reg dbuf (-500us, dynamic-indexed
// reg array spills to scratch). Only delta vs round 6: #pragma unroll 2 on
// the ci loop — two statically-indexed steps of straight-line code let the
// compiler hoist step-2 weight loads over step-1 FMAs. FMA order per output
// unchanged -> bitwise-identical results.
// X rows (B,Q,CIN) time-major, Wt layout (KS,CIN,COUT). ACT: 0=none 1=gelu 2=sigmoid.
template<int CIN, int COUT, int KS, int DIL, int ACT, int FEATS>
__global__ __launch_bounds__(256) void conv_gemm_k(
    const float* __restrict__ X, const float* __restrict__ Wt,
    const float* __restrict__ bias, float* __restrict__ Y)
{
    constexpr int TM   = 32;
    constexpr int HALO = (KS == 3) ? DIL : 0;
    constexpr int ROWS = TM + 2*HALO;
    constexpr int CPT  = COUT/64;
    __shared__ __align__(16) float As[ROWS*CIN];

    const int b  = blockIdx.y;
    const int t0 = blockIdx.x * TM;
    const int tid = threadIdx.x;

    if constexpr (FEATS) {
        for (int idx = tid; idx < TM*DD; idx += 256) {
            int r = idx >> 7, d = idx & (DD-1);
            int t = t0 + r;
            const float* xr = X + ((size_t)b*QLEN + t)*DD + d;
            float x    = xr[0];
            float xm1  = (t >= 1) ? xr[-DD]   : 0.f;
            float xm2  = (t >= 2) ? xr[-2*DD] : 0.f;
            float dy   = (t >= 1) ? (x - xm1)   : 0.f;
            float dym1 = (t >= 2) ? (xm1 - xm2) : 0.f;
            float ddy  = (t >= 1) ? (dy - dym1) : 0.f;
            As[r*CIN + d]        = x;
            As[r*CIN + DD + d]   = dy;
            As[r*CIN + 2*DD + d] = ddy;
        }
    } else {
        for (int idx = tid; idx < ROWS*(CIN/4); idx += 256) {
            int r = idx / (CIN/4), c4 = idx % (CIN/4);
            int gr = t0 + r - HALO;
            gr = gr < 0 ? 0 : (gr > QLEN-1 ? QLEN-1 : gr);   // edge padding
            float4 v = reinterpret_cast<const float4*>(X + ((size_t)b*QLEN + gr)*CIN)[c4];
            reinterpret_cast<float4*>(As)[r*(CIN/4) + c4] = v;
        }
    }
    __syncthreads();

    const int lane = tid & 63, rg = tid >> 6;
    const int c0 = lane * CPT;
    const int r0 = rg * 8;

    float acc[8][CPT];
    #pragma unroll
    for (int j = 0; j < 8; ++j)
        #pragma unroll
        for (int p = 0; p < CPT; ++p) acc[j][p] = 0.f;

    for (int k = 0; k < KS; ++k) {
        const float* Wk = Wt + (size_t)k*CIN*COUT + c0;
        #pragma unroll 2
        for (int ci = 0; ci < CIN; ci += 4) {
            float w[4][CPT];
            #pragma unroll
            for (int q = 0; q < 4; ++q) {
                if constexpr (CPT == 4) {
                    float4 wv = *reinterpret_cast<const float4*>(Wk + (size_t)(ci+q)*COUT);
                    w[q][0]=wv.x; w[q][1]=wv.y; w[q][2]=wv.z; w[q][3]=wv.w;
                } else {
                    float2 wv = *reinterpret_cast<const float2*>(Wk + (size_t)(ci+q)*COUT);
                    w[q][0]=wv.x; w[q][1]=wv.y;
                }
            }
            #pragma unroll
            for (int j = 0; j < 8; ++j) {
                const float4 a = *reinterpret_cast<const float4*>(&As[(r0 + j + k*DIL)*CIN + ci]);
                #pragma unroll
                for (int p = 0; p < CPT; ++p) {
                    acc[j][p] = fmaf(a.x, w[0][p], acc[j][p]);
                    acc[j][p] = fmaf(a.y, w[1][p], acc[j][p]);
                    acc[j][p] = fmaf(a.z, w[2][p], acc[j][p]);
                    acc[j][p] = fmaf(a.w, w[3][p], acc[j][p]);
                }
            }
        }
    }

    float bv[CPT];
    #pragma unroll
    for (int p = 0; p < CPT; ++p) bv[p] = bias[c0 + p];

    #pragma unroll
    for (int j = 0; j < 8; ++j) {
        float o[CPT];
        #pragma unroll
        for (int p = 0; p < CPT; ++p) {
            float v = acc[j][p] + bv[p];
            if constexpr (ACT == 1) v = geluf(v);
            if constexpr (ACT == 2) v = sigmf(v);
            o[p] = v;
        }
        float* yr = Y + ((size_t)b*QLEN + t0 + r0 + j)*COUT + c0;
        if constexpr (CPT == 4) {
            float4 ov; ov.x=o[0]; ov.y=o[1]; ov.z=o[2]; ov.w=o[3];
            *reinterpret_cast<float4*>(yr) = ov;
        } else {
            float2 ov; ov.x=o[0]; ov.y=o[1];
            *reinterpret_cast<float2*>(yr) = ov;
        }
    }
}

// ---------------------------------------------------------------------------
// LayerNorm over H=256 per (b,t) row with residual add.
__global__ __launch_bounds__(256) void ln_k(
    const float* __restrict__ X, const float* __restrict__ R,
    const float* __restrict__ w, const float* __restrict__ b,
    float* __restrict__ Y)
{
    int row  = blockIdx.x*4 + (threadIdx.x >> 6);
    int lane = threadIdx.x & 63;
    float4 v = reinterpret_cast<const float4*>(X + (size_t)row*HH)[lane];
    float4 rv = reinterpret_cast<const float4*>(R + (size_t)row*HH)[lane];
    v.x += rv.x; v.y += rv.y; v.z += rv.z; v.w += rv.w;
    float s = v.x + v.y + v.z + v.w;
    #pragma unroll
    for (int off = 32; off > 0; off >>= 1) s += __shfl_xor(s, off);
    float m = s * (1.0f/HH);
    float dx=v.x-m, dy=v.y-m, dz=v.z-m, dw=v.w-m;
    float q = dx*dx + dy*dy + dz*dz + dw*dw;
    #pragma unroll
    for (int off = 32; off > 0; off >>= 1) q += __shfl_xor(q, off);
    float inv = rsqrtf(q*(1.0f/HH) + 1e-5f);
    float4 wv = reinterpret_cast<const float4*>(w)[lane];
    float4 bv = reinterpret_cast<const float4*>(b)[lane];
    float4 o;
    o.x = dx*inv*wv.x + bv.x;
    o.y = dy*inv*wv.y + bv.y;
    o.z = dz*inv*wv.z + bv.z;
    o.w = dw*inv*wv.w + bv.w;
    reinterpret_cast<float4*>(Y + (size_t)row*HH)[lane] = o;
}

// ---------------------------------------------------------------------------
// Fused output-LN + rho/phi.
__global__ __launch_bounds__(256) void ln_rp_k(
    const float* __restrict__ X, const float* __restrict__ w, const float* __restrict__ b,
    const float* __restrict__ rpw, const float* __restrict__ rpb,
    float* __restrict__ Y, float* __restrict__ rho, float* __restrict__ phi)
{
    int row  = blockIdx.x*4 + (threadIdx.x >> 6);
    int lane = threadIdx.x & 63;
    float4 v = reinterpret_cast<const float4*>(X + (size_t)row*HH)[lane];
    float s = v.x + v.y + v.z + v.w;
    #pragma unroll
    for (int off = 32; off > 0; off >>= 1) s += __shfl_xor(s, off);
    float m = s * (1.0f/HH);
    float dx=v.x-m, dy=v.y-m, dz=v.z-m, dw=v.w-m;
    float q = dx*dx + dy*dy + dz*dz + dw*dw;
    #pragma unroll
    for (int off = 32; off > 0; off >>= 1) q += __shfl_xor(q, off);
    float inv = rsqrtf(q*(1.0f/HH) + 1e-5f);
    float4 wv = reinterpret_cast<const float4*>(w)[lane];
    float4 bv = reinterpret_cast<const float4*>(b)[lane];
    float4 o;
    o.x = dx*inv*wv.x + bv.x;
    o.y = dy*inv*wv.y + bv.y;
    o.z = dz*inv*wv.z + bv.z;
    o.w = dw*inv*wv.w + bv.w;
    reinterpret_cast<float4*>(Y + (size_t)row*HH)[lane] = o;

    float4 w0 = reinterpret_cast<const float4*>(rpw)[lane];
    float4 w1 = reinterpret_cast<const float4*>(rpw + HH)[lane];
    float d0 = o.x*w0.x + o.y*w0.y + o.z*w0.z + o.w*w0.w;
    float d1 = o.x*w1.x + o.y*w1.y + o.z*w1.z + o.w*w1.w;
    #pragma unroll
    for (int off = 32; off > 0; off >>= 1) { d0 += __shfl_xor(d0, off); d1 += __shfl_xor(d1, off); }
    if (lane == 0) {
        rho[row] = 1.25f * sigmf(d0 + rpb[0]);
        phi[row] = PI_F * tanhf(d1 + rpb[1]);
    }
}

// ---------------------------------------------------------------------------
// Kalman scan with next-step prefetch.
__global__ __launch_bounds__(64) void kalman_k(
    const float* __restrict__ Xin, const float* __restrict__ Kg,
    const float* __restrict__ rho_a, const float* __restrict__ phi_a,
    float* __restrict__ xpost)
{
    int b = blockIdx.x, l = threadIdx.x;
    const float* xb = Xin + (size_t)b*QLEN*DD;
    float re = xb[l], im = xb[64 + l];

    float rho_c = rho_a[b*QLEN], phi_c = phi_a[b*QLEN];
    const float* kg0 = Kg + (size_t)b*QLEN*DD;
    float kr_c = kg0[l], ki_c = kg0[64 + l];
    float y0_c = xb[l],  y1_c = xb[64 + l];

    for (int t = 0; t < QLEN; ++t) {
        float rho_n = 0.f, phi_n = 0.f, kr_n = 0.f, ki_n = 0.f, y0_n = 0.f, y1_n = 0.f;
        if (t + 1 < QLEN) {
            rho_n = rho_a[b*QLEN + t + 1];
            phi_n = phi_a[b*QLEN + t + 1];
            const float* kg = Kg + ((size_t)b*QLEN + t + 1)*DD;
            const float* yr = xb + (size_t)(t + 1)*DD;
            kr_n = kg[l]; ki_n = kg[64 + l];
            y0_n = yr[l]; y1_n = yr[64 + l];
        }
        float sn, cs; sincosf(phi_c, &sn, &cs);
        float pr = rho_c*(cs*re - sn*im);
        float pi = rho_c*(sn*re + cs*im);
        re = pr + kr_c*(y0_c - pr);
        im = pi + ki_c*(y1_c - pi);
        rho_c = rho_n; phi_c = phi_n; kr_c = kr_n; ki_c = ki_n; y0_c = y0_n; y1_c = y1_n;
    }
    xpost[b*DD + l]      = re;
    xpost[b*DD + 64 + l] = im;
}

// ---------------------------------------------------------------------------
// Rollout v5 (round-6 proven): one block/batch, 1024 threads, fp32 weights
// (precision-mandatory). ~119 GB/s/CU weight ingest = 83% of per-CU L2 port,
// near the 1-block/batch structural floor (876 us). Multi-block needs agent
// fences that invalidate L2 (round 4: FETCH 7.8MB -> 2.75GB, 2.4x slower).
__device__ __forceinline__ float bsum16(float v, float* red) {
    #pragma unroll
    for (int off = 32; off > 0; off >>= 1) v += __shfl_xor(v, off);
    __syncthreads();
    if ((threadIdx.x & 63) == 0) red[threadIdx.x >> 6] = v;
    __syncthreads();
    float s = 0.f;
    #pragma unroll
    for (int i = 0; i < 16; ++i) s += red[i];
    return s;
}
__device__ __forceinline__ float2 bsum16_2(float a, float b, float* red) {
    #pragma unroll
    for (int off = 32; off > 0; off >>= 1) { a += __shfl_xor(a, off); b += __shfl_xor(b, off); }
    __syncthreads();
    if ((threadIdx.x & 63) == 0) { red[threadIdx.x >> 6] = a; red[16 + (threadIdx.x >> 6)] = b; }
    __syncthreads();
    float sa = 0.f, sb = 0.f;
    #pragma unroll
    for (int i = 0; i < 16; ++i) { sa += red[i]; sb += red[16 + i]; }
    float2 r; r.x = sa; r.y = sb; return r;
}

__global__ __launch_bounds__(1024) void rollout_k5(
    const float* __restrict__ Hs, const float* __restrict__ xpost,
    const float4* __restrict__ Wri4,          // [96*256]  (j4, o)
    const float* __restrict__ rib,
    const float4* __restrict__ Wih4,          // [64*768]  (j4, gate_o)
    const float4* __restrict__ Whh4,          // [64*768]
    const float* __restrict__ bih, const float* __restrict__ bhh,
    const float* __restrict__ lnw, const float* __restrict__ lnb,
    const float* __restrict__ rpw, const float* __restrict__ rpb,
    float* __restrict__ out)
{
    __shared__ __align__(16) float hc[384];    // h_r[0:256] ++ curr[256:384]
    __shared__ __align__(16) float zsh[256];
    __shared__ float zpart[4][256];
    __shared__ float gpart[6][4][256];
    __shared__ float red[32];

    const int tid = threadIdx.x;
    const int o = tid & 255, p = tid >> 8;
    const int b = blockIdx.x;

    if (p == 0) hc[o] = Hs[((size_t)b*QLEN + QLEN-1)*HH + o];
    if (p == 1 && o < DD) hc[HH + o] = xpost[b*DD + o];

    const float bi0 = bih[o],    bi1 = bih[HH+o], bi2 = bih[2*HH+o];
    const float bh0 = bhh[o],    bh1 = bhh[HH+o], bh2 = bhh[2*HH+o];
    const float rb  = rib[o];
    const float lw  = lnw[o],    lb  = lnb[o];
    const float rw0 = rpw[o],    rw1 = rpw[HH+o];
    const float rpb0 = rpb[0],   rpb1 = rpb[1];
    const float4* hc4 = reinterpret_cast<const float4*>(hc);
    const float4* zf4 = reinterpret_cast<const float4*>(zsh);
    __syncthreads();

    for (int s = 0; s < WOUT; ++s) {
        // ---- Phase A: z-partials (Wri) + e-partials (Whh) — both need only h
        float az = 0.f;
        {
            const float4* wp = Wri4 + (size_t)(p*24)*256 + o;
            #pragma unroll 8
            for (int j4 = 0; j4 < 24; ++j4) {
                float4 w = wp[(size_t)j4*256];
                float4 h = hc4[p*24 + j4];
                az = fmaf(w.x, h.x, az); az = fmaf(w.y, h.y, az);
                az = fmaf(w.z, h.z, az); az = fmaf(w.w, h.w, az);
            }
        }
        float e0=0.f, e1=0.f, e2=0.f;
        {
            const float4* whp = Whh4 + (size_t)(p*16)*768 + o;
            #pragma unroll 4
            for (int j4 = 0; j4 < 16; ++j4) {
                float4 h = hc4[p*16 + j4];
                float4 wd = whp[(size_t)j4*768];
                float4 we = whp[(size_t)j4*768 + 256];
                float4 wf = whp[(size_t)j4*768 + 512];
                e0 = fmaf(wd.x,h.x,e0); e0 = fmaf(wd.y,h.y,e0); e0 = fmaf(wd.z,h.z,e0); e0 = fmaf(wd.w,h.w,e0);
                e1 = fmaf(we.x,h.x,e1); e1 = fmaf(we.y,h.y,e1); e1 = fmaf(we.z,h.z,e1); e1 = fmaf(we.w,h.w,e1);
                e2 = fmaf(wf.x,h.x,e2); e2 = fmaf(wf.y,h.y,e2); e2 = fmaf(wf.z,h.z,e2); e2 = fmaf(wf.w,h.w,e2);
            }
        }
        zpart[p][o] = az;
        gpart[3][p][o]=e0; gpart[4][p][o]=e1; gpart[5][p][o]=e2;
        __syncthreads();
        if (p == 0)
            zsh[o] = tanhf(zpart[0][o]+zpart[1][o]+zpart[2][o]+zpart[3][o] + rb);
        __syncthreads();

        // ---- Phase B: g-partials (Wih)
        float g0=0.f, g1=0.f, g2=0.f;
        {
            const float4* wip = Wih4 + (size_t)(p*16)*768 + o;
            #pragma unroll 4
            for (int j4 = 0; j4 < 16; ++j4) {
                float4 z = zf4[p*16 + j4];
                float4 wa = wip[(size_t)j4*768];
                float4 wb = wip[(size_t)j4*768 + 256];
                float4 wc = wip[(size_t)j4*768 + 512];
                g0 = fmaf(wa.x,z.x,g0); g0 = fmaf(wa.y,z.y,g0); g0 = fmaf(wa.z,z.z,g0); g0 = fmaf(wa.w,z.w,g0);
                g1 = fmaf(wb.x,z.x,g1); g1 = fmaf(wb.y,z.y,g1); g1 = fmaf(wb.z,z.z,g1); g1 = fmaf(wb.w,z.w,g1);
                g2 = fmaf(wc.x,z.x,g2); g2 = fmaf(wc.y,z.y,g2); g2 = fmaf(wc.z,z.z,g2); g2 = fmaf(wc.w,z.w,g2);
            }
        }
        gpart[0][p][o]=g0; gpart[1][p][o]=g1; gpart[2][p][o]=g2;
        __syncthreads();

        float go = 0.f;
        if (p == 0) {
            float G0 = gpart[0][0][o]+gpart[0][1][o]+gpart[0][2][o]+gpart[0][3][o] + bi0;
            float G1 = gpart[1][0][o]+gpart[1][1][o]+gpart[1][2][o]+gpart[1][3][o] + bi1;
            float G2 = gpart[2][0][o]+gpart[2][1][o]+gpart[2][2][o]+gpart[2][3][o] + bi2;
            float E0 = gpart[3][0][o]+gpart[3][1][o]+gpart[3][2][o]+gpart[3][3][o] + bh0;
            float E1 = gpart[4][0][o]+gpart[4][1][o]+gpart[4][2][o]+gpart[4][3][o] + bh1;
            float E2 = gpart[5][0][o]+gpart[5][1][o]+gpart[5][2][o]+gpart[5][3][o] + bh2;
            float r  = sigmf(G0 + E0);
            float zg = sigmf(G1 + E1);
            float n  = tanhf(G2 + r*E2);
            go = (1.0f - zg)*n + zg*hc[o];
        }

        // ---- LN over 256 (two-pass, matches reference order)
        float m   = bsum16(go, red) * (1.0f/HH);
        float d   = (p == 0) ? (go - m) : 0.f;
        float var = bsum16(d*d, red) * (1.0f/HH);
        float hn  = (p == 0) ? (d * rsqrtf(var + 1e-5f) * lw + lb) : 0.f;

        // ---- rho/phi: fused dual reduction
        float2 ps = bsum16_2((p == 0) ? hn*rw0 : 0.f, (p == 0) ? hn*rw1 : 0.f, red);
        float rho = 1.25f * sigmf(ps.x + rpb0);
        float phi = PI_F * tanhf(ps.y + rpb1);
        float sn, cs; sincosf(phi, &sn, &cs);

        if (p == 0) hc[o] = hn;
        if (tid < 64) {
            float cre = hc[HH + tid], cim = hc[HH + 64 + tid];
            float nr = rho*(cs*cre - sn*cim);
            float ni = rho*(sn*cre + cs*cim);
            hc[HH + tid] = nr; hc[HH + 64 + tid] = ni;
            float* ob = out + ((size_t)b*WOUT + s)*DD;
            ob[tid] = nr; ob[64 + tid] = ni;
        }
        __syncthreads();
    }
}

// ---------------------------------------------------------------------------
extern "C" void kernel_launch(void* const* d_in, const int* in_sizes, int n_in,
                              void* d_out, int out_size, void* d_ws, size_t ws_size,
                              hipStream_t stream)
{
    const float* x_in   = (const float*)d_in[0];
    const float* inp_w  = (const float*)d_in[2];
    const float* inp_b  = (const float*)d_in[3];
    const float* b0c1w  = (const float*)d_in[4];
    const float* b0c1b  = (const float*)d_in[5];
    const float* b0c2w  = (const float*)d_in[6];
    const float* b0c2b  = (const float*)d_in[7];
    const float* b0lnw  = (const float*)d_in[8];
    const float* b0lnb  = (const float*)d_in[9];
    const float* b1c1w  = (const float*)d_in[10];
    const float* b1c1b  = (const float*)d_in[11];
    const float* b1c2w  = (const float*)d_in[12];
    const float* b1c2b  = (const float*)d_in[13];
    const float* b1lnw  = (const float*)d_in[14];
    const float* b1lnb  = (const float*)d_in[15];
    const float* olnw   = (const float*)d_in[16];
    const float* olnb   = (const float*)d_in[17];
    const float* gainw  = (const float*)d_in[18];
    const float* gainb  = (const float*)d_in[19];
    const float* rpw    = (const float*)d_in[20];
    const float* rpb    = (const float*)d_in[21];
    const float* riw    = (const float*)d_in[22];
    const float* rib    = (const float*)d_in[23];
    const float* wih    = (const float*)d_in[24];
    const float* whh    = (const float*)d_in[25];
    const float* bih    = (const float*)d_in[26];
    const float* bhh    = (const float*)d_in[27];
    const float* rlnw   = (const float*)d_in[28];
    const float* rlnb   = (const float*)d_in[29];
    const float* rprw   = (const float*)d_in[30];
    const float* rprb   = (const float*)d_in[31];
    float* out = (float*)d_out;

    // workspace layout (floats)
    float* ws   = (float*)d_ws;
    float* buf0 = ws;                    // 8388608
    float* buf1 = ws +  8388608;         // 8388608
    float* buf2 = ws + 16777216;         // 8388608
    float* Kg    = buf2;                 // 4194304 (buf2 dead by then)
    float* rhoA  = buf2 + 4194304;       // 32768
    float* phiA  = rhoA + 32768;         // 32768
    float* xpost = phiA + 32768;         // 8192
    float* wts   = ws + 25165824;
    float* Wt_inp  = wts;                //  98304
    float* Wt_b0c1 = wts +   98304;      // 196608
    float* Wt_b0c2 = wts +  294912;      // 196608
    float* Wt_b1c1 = wts +  491520;      // 196608
    float* Wt_b1c2 = wts +  688128;      // 196608
    float* Wt_gain = wts +  884736;      //  32768
    float4* Wri4   = (float4*)(wts +  917504);   // 24576 float4
    float4* Wih4   = (float4*)(wts + 1015808);   // 49152 float4
    float4* Whh4   = (float4*)(wts + 1212416);   // 49152 float4
    // total ws use: 26574848 floats ~= 101.4 MB

    // ---- fused weight prep
    prep_k<<<4064, 256, 0, stream>>>(inp_w, b0c1w, b0c2w, b1c1w, b1c2w, gainw,
                                     riw, wih, whh,
                                     Wt_inp, Wt_b0c1, Wt_b0c2, Wt_b1c1, Wt_b1c2,
                                     Wt_gain, Wri4, Wih4, Whh4);

    dim3 cg32(QLEN/32, NB);

    // ---- input projection (feats built on the fly): x_in -> buf0
    conv_gemm_k<384,256,1,1,0,1><<<cg32, 256, 0, stream>>>(x_in, Wt_inp, inp_b, buf0);

    // ---- block 0 (dil=1)
    conv_gemm_k<256,256,3,1,1,0><<<cg32, 256, 0, stream>>>(buf0, Wt_b0c1, b0c1b, buf1);
    conv_gemm_k<256,256,3,1,1,0><<<cg32, 256, 0, stream>>>(buf1, Wt_b0c2, b0c2b, buf2);
    ln_k<<<NB*QLEN/4, 256, 0, stream>>>(buf0, buf2, b0lnw, b0lnb, buf1);

    // ---- block 1 (dil=2)
    conv_gemm_k<256,256,3,2,1,0><<<cg32, 256, 0, stream>>>(buf1, Wt_b1c1, b1c1b, buf0);
    conv_gemm_k<256,256,3,2,1,0><<<cg32, 256, 0, stream>>>(buf0, Wt_b1c2, b1c2b, buf2);
    ln_k<<<NB*QLEN/4, 256, 0, stream>>>(buf1, buf2, b1lnw, b1lnb, buf0);

    // ---- fused output LN + rho/phi: buf0 -> buf1, rhoA, phiA
    ln_rp_k<<<NB*QLEN/4, 256, 0, stream>>>(buf0, olnw, olnb, rpw, rpb,
                                           buf1, rhoA, phiA);

    // ---- Kg (sigmoid GEMM, small)
    conv_gemm_k<256,128,1,1,2,0><<<cg32, 256, 0, stream>>>(buf1, Wt_gain, gainb, Kg);

    // ---- Kalman scan (prefetch-pipelined)
    kalman_k<<<NB, 64, 0, stream>>>(x_in, Kg, rhoA, phiA, xpost);

    // ---- rollout v5 (fp32 precision-mandatory)
    rollout_k5<<<NB, 1024, 0, stream>>>(buf1, xpost, Wri4, rib, Wih4, Whh4,
                                        bih, bhh, rlnw, rlnb, rprw, rprb, out);
}